// Round 8
// baseline (39.859 us; speedup 1.0000x reference)
//
#include <hip/hip_runtime.h>
#include <hip/hip_bf16.h>

#define DD 256
#define NROWS 16384
#define BR 32  // rows per block; 512 blocks, 4 waves each

typedef float f32x4 __attribute__((ext_vector_type(4)));
typedef __bf16 bf16x4 __attribute__((ext_vector_type(4)));
typedef __bf16 bf16x8 __attribute__((ext_vector_type(8)));

__device__ __forceinline__ bf16x8 cvt8(f32x4 lo, f32x4 hi) {
  bf16x8 v;
#pragma unroll
  for (int j = 0; j < 4; ++j) {
    v[j] = (__bf16)lo[j];
    v[4 + j] = (__bf16)hi[j];
  }
  return v;
}

// ---------------------------------------------------------------------------
// ONE launch, no cross-block deps (A/B vs R5/R7's two-launch 31us floor):
//   t   = x_blk @ Wv^T + bv    (bf16, swizzled LDS)
//   out = x + t @ Wout^T + bout
// Per block: 32 x-rows. Wave w owns cols [64w, 64w+64) of t (GEMM1) and of
// out (GEMM2). Validated tile pattern (R5/R7): mfma(A=weight row frag,
// B=x/t row frag) -> D col(l&15)=row-in-tile, D rowquad g*4+reg = 4 consec
// out-cols -> f32x4 epilogue. XOR swizzle byte^=(row&7)<<4 on 512B rows.
// 16 waves/CU (4 blocks/CU, 32KB LDS); weights stream L2->VGPR batched.
// ---------------------------------------------------------------------------
__global__ __launch_bounds__(256, 4) void fused_knn(
    const float* __restrict__ x, const float* __restrict__ Wqkv,
    const float* __restrict__ bqkv, const float* __restrict__ Wout,
    const float* __restrict__ bout, float* __restrict__ out) {
  __shared__ __bf16 xs[BR * DD];  // 16 KiB
  __shared__ __bf16 ts[BR * DD];  // 16 KiB

  const int t = threadIdx.x;
  const int w = t >> 6, l = t & 63;
  const int R0 = blockIdx.x * BR;
  const int lr = l & 15;  // row-in-tile
  const int g = l >> 4;   // k-group
  const int lk = g * 8;   // k offset (elements)

  const float* __restrict__ Wv = Wqkv + 2 * DD * DD;
  const float* __restrict__ bv = bqkv + 2 * DD;

  // ---- Stage x tile (32 x 256 f32 -> bf16, swizzled). 8 f32x4 loads/thread.
  {
    const int r = t >> 3, seg = t & 7;  // row, 32-col segment
    const float* src = x + (size_t)(R0 + r) * DD + seg * 32;
    const int sw = (r & 7) << 4;
#pragma unroll
    for (int h = 0; h < 4; ++h) {
      f32x4 lo = *(const f32x4*)(src + h * 8);
      f32x4 hi = *(const f32x4*)(src + h * 8 + 4);
      *(bf16x8*)((char*)xs + ((r * 512 + seg * 64 + h * 16) ^ sw)) =
          cvt8(lo, hi);
    }
  }
  __syncthreads();

  const int sw0 = (lr & 7) << 4;          // swizzle for rows 0..15 (row=lr)
  const int sw1 = ((16 + lr) & 7) << 4;   // rows 16..31 (row=16+lr)

  // ---- GEMM1: t = x @ Wv^T + bv (wave w -> v-cols [64w, 64w+64)).
#pragma unroll
  for (int ct = 0; ct < 4; ++ct) {
    const float* ap = Wv + (size_t)(w * 64 + ct * 16 + lr) * DD + lk;
    bf16x8 af[8];
#pragma unroll
    for (int ks = 0; ks < 8; ++ks) {  // 16 independent dwordx4, then cvt
      f32x4 lo = *(const f32x4*)(ap + ks * 32);
      f32x4 hi = *(const f32x4*)(ap + ks * 32 + 4);
      af[ks] = cvt8(lo, hi);
    }
    f32x4 a0 = {0.f, 0.f, 0.f, 0.f}, a1 = {0.f, 0.f, 0.f, 0.f};
#pragma unroll
    for (int ks = 0; ks < 8; ++ks) {
      const int kb = (lk + ks * 32) * 2;
      bf16x8 b0 = *(const bf16x8*)((const char*)xs + ((lr * 512 + kb) ^ sw0));
      bf16x8 b1 =
          *(const bf16x8*)((const char*)xs + (((16 + lr) * 512 + kb) ^ sw1));
      a0 = __builtin_amdgcn_mfma_f32_16x16x32_bf16(af[ks], b0, a0, 0, 0, 0);
      a1 = __builtin_amdgcn_mfma_f32_16x16x32_bf16(af[ks], b1, a1, 0, 0, 0);
    }
    // t[row][vcol..vcol+3] for row tiles {lr, 16+lr}; + bv, bf16, swizzled.
    const int vcol = w * 64 + ct * 16 + g * 4;
    f32x4 bq = *(const f32x4*)(bv + vcol);
    a0 += bq;
    a1 += bq;
    bf16x4 o0, o1;
#pragma unroll
    for (int j = 0; j < 4; ++j) {
      o0[j] = (__bf16)a0[j];
      o1[j] = (__bf16)a1[j];
    }
    *(bf16x4*)((char*)ts + ((lr * 512 + vcol * 2) ^ sw0)) = o0;
    *(bf16x4*)((char*)ts + (((16 + lr) * 512 + vcol * 2) ^ sw1)) = o1;
  }
  __syncthreads();

  // ---- GEMM2: out = x + t @ Wout^T + bout (wave w -> out-cols [64w,+64)).
#pragma unroll
  for (int ct = 0; ct < 4; ++ct) {
    const float* ap = Wout + (size_t)(w * 64 + ct * 16 + lr) * DD + lk;
    bf16x8 af[8];
#pragma unroll
    for (int ks = 0; ks < 8; ++ks) {
      f32x4 lo = *(const f32x4*)(ap + ks * 32);
      f32x4 hi = *(const f32x4*)(ap + ks * 32 + 4);
      af[ks] = cvt8(lo, hi);
    }
    f32x4 a0 = {0.f, 0.f, 0.f, 0.f}, a1 = {0.f, 0.f, 0.f, 0.f};
#pragma unroll
    for (int ks = 0; ks < 8; ++ks) {
      const int kb = (lk + ks * 32) * 2;
      bf16x8 b0 = *(const bf16x8*)((const char*)ts + ((lr * 512 + kb) ^ sw0));
      bf16x8 b1 =
          *(const bf16x8*)((const char*)ts + (((16 + lr) * 512 + kb) ^ sw1));
      a0 = __builtin_amdgcn_mfma_f32_16x16x32_bf16(af[ks], b0, a0, 0, 0, 0);
      a1 = __builtin_amdgcn_mfma_f32_16x16x32_bf16(af[ks], b1, a1, 0, 0, 0);
    }
    const int ocol = w * 64 + ct * 16 + g * 4;
    f32x4 bo = *(const f32x4*)(bout + ocol);
    const size_t i0 = (size_t)(R0 + lr) * DD + ocol;
    const size_t i1 = (size_t)(R0 + 16 + lr) * DD + ocol;
    f32x4 x0 = *(const f32x4*)(x + i0);  // exact fp32 residual (L2/L3 hot)
    f32x4 x1 = *(const f32x4*)(x + i1);
    *(f32x4*)(out + i0) = a0 + x0 + bo;
    *(f32x4*)(out + i1) = a1 + x1 + bo;
  }
}

extern "C" void kernel_launch(void* const* d_in, const int* in_sizes, int n_in,
                              void* d_out, int out_size, void* d_ws, size_t ws_size,
                              hipStream_t stream) {
  const float* x = (const float*)d_in[0];
  const float* Wqkv = (const float*)d_in[1];
  const float* bqkv = (const float*)d_in[2];
  const float* Wout = (const float*)d_in[3];
  const float* bout = (const float*)d_in[4];
  float* out = (float*)d_out;

  fused_knn<<<NROWS / BR, 256, 0, stream>>>(x, Wqkv, bqkv, Wout, bout, out);
}